// Round 1
// baseline (181.934 us; speedup 1.0000x reference)
//
#include <hip/hip_runtime.h>

#define T_ 4
#define B_ 8
#define N_ 1024
#define C_ 512
#define H_ 8
#define D_ 64
#define M_ (T_*B_*N_)   // 32768 rows
#define TB_ (T_*B_)     // 32

typedef __bf16 bf16;
typedef __bf16 bf16x4 __attribute__((ext_vector_type(4)));
typedef __bf16 bf16x8 __attribute__((ext_vector_type(8)));
typedef float f32x4 __attribute__((ext_vector_type(4)));

__device__ __forceinline__ void gload16(const void* g, void* l) {
  __builtin_amdgcn_global_load_lds(
      (const __attribute__((address_space(1))) void*)g,
      (__attribute__((address_space(3))) void*)l, 16, 0, 0);
}

// ---- fold BN into weights: W'[d,c] = W[d,c]*s[d], bias'[d] = (b-mu)*s + beta ----
__global__ void prep_w(const float* __restrict__ W, const float* __restrict__ b,
                       const float* __restrict__ g, const float* __restrict__ beta,
                       const float* __restrict__ mu, const float* __restrict__ var,
                       bf16* __restrict__ Wout, float* __restrict__ biasOut) {
  int d = blockIdx.x;
  float s = g[d] * rsqrtf(var[d] + 1e-5f);
  if (threadIdx.x == 0) biasOut[d] = (b[d] - mu[d]) * s + beta[d];
  for (int c = threadIdx.x; c < C_; c += blockDim.x)
    Wout[d * C_ + c] = (bf16)(W[d * C_ + c] * s);
}

// ---- x (f32) -> bf16 ----
__global__ void cvt_x(const float* __restrict__ x, bf16* __restrict__ xb) {
  const int n4 = (M_ * C_) / 4;
  for (int i = blockIdx.x * blockDim.x + threadIdx.x; i < n4;
       i += gridDim.x * blockDim.x) {
    float4 f = ((const float4*)x)[i];
    bf16x4 o; o[0] = (bf16)f.x; o[1] = (bf16)f.y; o[2] = (bf16)f.z; o[3] = (bf16)f.w;
    ((bf16x4*)xb)[i] = o;
  }
}

// ---- GEMM: C[m][j] = sum_c A[m][c] * Bt[j][c]  (Bt row-major N x K) ----
// QKV: Bt has 1536 rows (Wq',Wk',Wv'), out = bf16, three mats at stride M_*C_.
// !QKV: Bt has 512 rows (Wp'), out = f32 with bias.
template <bool QKV>
__global__ __launch_bounds__(256, 2)
void gemm_bt(const bf16* __restrict__ A, const bf16* __restrict__ Bt,
             const float* __restrict__ bias,
             bf16* __restrict__ outb, float* __restrict__ outf) {
  const int K = C_;
  __shared__ bf16 As[128][32];
  __shared__ bf16 Bs[128][32];
  const int tid = threadIdx.x;
  const int w = tid >> 6, l = tid & 63;
  const int wm = w >> 1, wn = w & 1;
  const int m0 = blockIdx.x * 128, n0 = blockIdx.y * 128;

  f32x4 acc[4][4] = {};

  const int r4 = l >> 2;            // staging: lane -> row within 16-row chunk
  const int c4 = (l & 3) * 8;       // staging: lane -> 8-elem k-chunk
  for (int kk = 0; kk < K; kk += 32) {
#pragma unroll
    for (int i = 0; i < 2; i++) {
      int qi = 2 * w + i;           // 8 one-KB chunks, 2 per wave
      gload16(A  + (size_t)(m0 + 16 * qi + r4) * K + kk + c4, &As[16 * qi][0]);
      gload16(Bt + (size_t)(n0 + 16 * qi + r4) * K + kk + c4, &Bs[16 * qi][0]);
    }
    __syncthreads();
    bf16x8 af[4], bfr[4];
#pragma unroll
    for (int t = 0; t < 4; t++) {
      af[t]  = *(const bf16x8*)&As[wm * 64 + t * 16 + (l & 15)][(l >> 4) * 8];
      bfr[t] = *(const bf16x8*)&Bs[wn * 64 + t * 16 + (l & 15)][(l >> 4) * 8];
    }
#pragma unroll
    for (int mt = 0; mt < 4; mt++)
#pragma unroll
      for (int nt = 0; nt < 4; nt++)
        acc[mt][nt] = __builtin_amdgcn_mfma_f32_16x16x32_bf16(
            af[mt], bfr[nt], acc[mt][nt], 0, 0, 0);
    __syncthreads();
  }

  // epilogue: C/D layout col = lane&15, row = (lane>>4)*4 + reg
#pragma unroll
  for (int mt = 0; mt < 4; mt++)
#pragma unroll
    for (int nt = 0; nt < 4; nt++) {
      int j = n0 + wn * 64 + nt * 16 + (l & 15);
      float bj = bias[j];
      if (QKV) {
        int mat = j >> 9, jj = j & 511;
        bf16* op = outb + (size_t)mat * ((size_t)M_ * C_);
#pragma unroll
        for (int r = 0; r < 4; r++) {
          int m = m0 + wm * 64 + mt * 16 + (l >> 4) * 4 + r;
          op[(size_t)m * C_ + jj] = (bf16)(acc[mt][nt][r] + bj);
        }
      } else {
#pragma unroll
        for (int r = 0; r < 4; r++) {
          int m = m0 + wm * 64 + mt * 16 + (l >> 4) * 4 + r;
          outf[(size_t)m * C_ + j] = acc[mt][nt][r] + bj;
        }
      }
    }
}

// ---- kv partials: kvp[part][g][d][e] = sum_{n in part} k[n,d]*v[n,e] ----
// g = (t*B+b)*H + h ; k,v stored (t,b,n,c) bf16, head slice c = h*64..h*64+63
__global__ __launch_bounds__(256)
void kv_kernel(const bf16* __restrict__ kmat, const bf16* __restrict__ vmat,
               float* __restrict__ kvp) {
  const int g = blockIdx.x & 255, part = blockIdx.x >> 8;
  const int tb = g >> 3, h = g & 7;
  const int w = threadIdx.x >> 6, l = threadIdx.x & 63;
  const bf16* kb = kmat + (size_t)tb * N_ * C_ + h * 64;
  const bf16* vb = vmat + (size_t)tb * N_ * C_ + h * 64;

  f32x4 acc[4] = {};
  for (int n0 = part * 256; n0 < part * 256 + 256; n0 += 32) {
    bf16x8 a, bv[4];
#pragma unroll
    for (int e = 0; e < 8; e++) {
      size_t row = (size_t)(n0 + (l >> 4) * 8 + e) * C_;
      a[e] = kb[row + 16 * w + (l & 15)];       // A[d][n] = k[n][d], m-tile = wave
#pragma unroll
      for (int nt = 0; nt < 4; nt++)
        bv[nt][e] = vb[row + nt * 16 + (l & 15)];
    }
#pragma unroll
    for (int nt = 0; nt < 4; nt++)
      acc[nt] = __builtin_amdgcn_mfma_f32_16x16x32_bf16(a, bv[nt], acc[nt], 0, 0, 0);
  }
#pragma unroll
  for (int nt = 0; nt < 4; nt++)
#pragma unroll
    for (int r = 0; r < 4; r++) {
      int d = 16 * w + (l >> 4) * 4 + r, e = nt * 16 + (l & 15);
      kvp[((size_t)(part * 256 + g)) * 4096 + d * 64 + e] = acc[nt][r];
    }
}

// ---- y[n][e] = sum_d q[n][d] * kv[d][e]   (kv = sum of 4 partials, scaled 1/N) ----
__global__ __launch_bounds__(256)
void y_kernel(const bf16* __restrict__ q, const float* __restrict__ kvp,
              bf16* __restrict__ y) {
  const int g = blockIdx.x >> 2, chunk = blockIdx.x & 3;
  const int tb = g >> 3, h = g & 7;
  const int w = threadIdx.x >> 6, l = threadIdx.x & 63;
  const bf16* qb = q + (size_t)tb * N_ * C_ + h * 64;
  bf16* yb = y + (size_t)tb * N_ * C_ + h * 64;

  // B-frags for the 64x64 kv, held in registers: B[k=d][n'=e]
  bf16x8 bf[2][4];
#pragma unroll
  for (int ks = 0; ks < 2; ks++)
#pragma unroll
    for (int nt = 0; nt < 4; nt++)
#pragma unroll
      for (int e = 0; e < 8; e++) {
        int idx = (ks * 32 + (l >> 4) * 8 + e) * 64 + nt * 16 + (l & 15);
        float s = 0.f;
#pragma unroll
        for (int p = 0; p < 4; p++)
          s += kvp[((size_t)(p * 256 + g)) * 4096 + idx];
        bf[ks][nt][e] = (bf16)(s * (1.f / (float)N_));
      }

  for (int t = w; t < 16; t += 4) {
    int n0 = chunk * 256 + t * 16;
    f32x4 acc[4] = {};
#pragma unroll
    for (int ks = 0; ks < 2; ks++) {
      bf16x8 a = *(const bf16x8*)(qb + (size_t)(n0 + (l & 15)) * C_ + ks * 32 + (l >> 4) * 8);
#pragma unroll
      for (int nt = 0; nt < 4; nt++)
        acc[nt] = __builtin_amdgcn_mfma_f32_16x16x32_bf16(a, bf[ks][nt], acc[nt], 0, 0, 0);
    }
#pragma unroll
    for (int nt = 0; nt < 4; nt++)
#pragma unroll
      for (int r = 0; r < 4; r++) {
        int n = n0 + (l >> 4) * 4 + r, e = nt * 16 + (l & 15);
        yb[(size_t)n * C_ + e] = (bf16)acc[nt][r];
      }
  }
}

extern "C" void kernel_launch(void* const* d_in, const int* in_sizes, int n_in,
                              void* d_out, int out_size, void* d_ws, size_t ws_size,
                              hipStream_t stream) {
  const float* x = (const float*)d_in[0];
  char* ws = (char*)d_ws;
  // ws layout (bytes):
  bf16* xb   = (bf16*)(ws + 0);            // 33.5 MB, later reused as y
  bf16* q    = (bf16*)(ws + 33554432);     // 33.5 MB
  bf16* kk   = (bf16*)(ws + 67108864);     // 33.5 MB
  bf16* vv   = (bf16*)(ws + 100663296);    // 33.5 MB
  float* kvp = (float*)(ws + 134217728);   // [4][256][64][64] f32 = 16 MB
  bf16* WB   = (bf16*)(ws + 150994944);    // [4][512][512] bf16 = 2 MB
  float* BS  = (float*)(ws + 153092096);   // [4][512] f32
  (void)in_sizes; (void)n_in; (void)out_size; (void)ws_size;

  for (int mat = 0; mat < 4; mat++) {
    const float* W    = (const float*)d_in[1 + 6 * mat + 0];
    const float* bb   = (const float*)d_in[1 + 6 * mat + 1];
    const float* gg   = (const float*)d_in[1 + 6 * mat + 2];
    const float* beta = (const float*)d_in[1 + 6 * mat + 3];
    const float* mu   = (const float*)d_in[1 + 6 * mat + 4];
    const float* var  = (const float*)d_in[1 + 6 * mat + 5];
    prep_w<<<512, 256, 0, stream>>>(W, bb, gg, beta, mu, var,
                                    WB + (size_t)mat * C_ * C_, BS + mat * C_);
  }
  cvt_x<<<2048, 256, 0, stream>>>(x, xb);
  // q,k,v contiguous => one fused GEMM over 1536 output channels
  gemm_bt<true><<<dim3(256, 12), 256, 0, stream>>>(xb, WB, BS, q, nullptr);
  kv_kernel<<<1024, 256, 0, stream>>>(kk, vv, kvp);
  y_kernel<<<1024, 256, 0, stream>>>(q, kvp, xb /* = y */);
  gemm_bt<false><<<dim3(256, 4), 256, 0, stream>>>(
      xb /* = y */, WB + 3 * (size_t)C_ * C_, BS + 3 * C_, nullptr, (float*)d_out);
}

// Round 2
// 169.437 us; speedup vs baseline: 1.0738x; 1.0738x over previous
//
#include <hip/hip_runtime.h>

#define T_ 4
#define B_ 8
#define N_ 1024
#define C_ 512
#define H_ 8
#define D_ 64
#define M_ (T_*B_*N_)   // 32768 rows
#define TB_ (T_*B_)     // 32

typedef __bf16 bf16;
typedef __bf16 bf16x4 __attribute__((ext_vector_type(4)));
typedef __bf16 bf16x8 __attribute__((ext_vector_type(8)));
typedef float f32x4 __attribute__((ext_vector_type(4)));

__device__ __forceinline__ void gload16(const void* g, void* l) {
  __builtin_amdgcn_global_load_lds(
      (const __attribute__((address_space(1))) void*)g,
      (__attribute__((address_space(3))) void*)l, 16, 0, 0);
}

// ---- fold BN into weights: W'[d,c] = W[d,c]*s[d], bias'[d] = (b-mu)*s + beta ----
__global__ void prep_w(const float* __restrict__ W, const float* __restrict__ b,
                       const float* __restrict__ g, const float* __restrict__ beta,
                       const float* __restrict__ mu, const float* __restrict__ var,
                       bf16* __restrict__ Wout, float* __restrict__ biasOut) {
  int d = blockIdx.x;
  float s = g[d] * rsqrtf(var[d] + 1e-5f);
  if (threadIdx.x == 0) biasOut[d] = (b[d] - mu[d]) * s + beta[d];
  for (int c = threadIdx.x; c < C_; c += blockDim.x)
    Wout[d * C_ + c] = (bf16)(W[d * C_ + c] * s);
}

// ---- x (f32) -> bf16 ----
__global__ void cvt_x(const float* __restrict__ x, bf16* __restrict__ xb) {
  const int n4 = (M_ * C_) / 4;
  for (int i = blockIdx.x * blockDim.x + threadIdx.x; i < n4;
       i += gridDim.x * blockDim.x) {
    float4 f = ((const float4*)x)[i];
    bf16x4 o; o[0] = (bf16)f.x; o[1] = (bf16)f.y; o[2] = (bf16)f.z; o[3] = (bf16)f.w;
    ((bf16x4*)xb)[i] = o;
  }
}

// =====================================================================
// 256x256-tile, BK=64, 8-wave, double-buffered, 8-phase GEMM.
// C[m][j] = sum_c A[m][c] * Bt[j][c], K = 512. Bt row-major [NB*256][512].
// LDS: sm[buf][A/B][256][64] bf16, XOR-swizzled on 16B chunks (chunk ^= row&7).
// Staging: global_load_lds (linear LDS dest) with inverse-swizzled global src.
// Phases per iter (tiles e=2i in buf0, o=2i+1 in buf1):
//   P1 dsA(b0,mh0)+dsB(b0,nh0) | stg o.A0->b1 | MFMA(0,0)
//   P2 dsB(b0,nh1)             | stg o.A1->b1 | MFMA(0,1)
//   P3 dsA(b0,mh1)             | stg e2.B0->b0| MFMA(1,0)
//   P4                         | stg e2.B1->b0| MFMA(1,1) vmcnt(4)
//   P5 dsA(b1,mh0)+dsB(b1,nh0) | stg e2.A0->b0| MFMA(0,0)
//   P6 dsB(b1,nh1)             | stg e2.A1->b0| MFMA(0,1)
//   P7 dsA(b1,mh1)             | stg o2.B0->b1| MFMA(1,0)
//   P8                         | stg o2.B1->b1| MFMA(1,1) vmcnt(4)
// =====================================================================
template <int NB, bool QKV>
__global__ __launch_bounds__(512, 2)
void gemm8(const bf16* __restrict__ A, const bf16* __restrict__ Bt,
           const float* __restrict__ bias,
           bf16* __restrict__ outb, float* __restrict__ outf) {
  __shared__ __align__(16) bf16 sm[2][2][256][64];   // 128 KiB
  const int tid = threadIdx.x;
  const int wv = tid >> 6, l = tid & 63;
  const int wm = wv >> 2, wn = wv & 3;
  const int lr = l & 15, lq = l >> 4, l7 = l & 7, lh = l >> 3;
  const int lc8 = (l7 ^ lh) * 8;   // inverse-swizzled source chunk for staging

  // T1: bijective XCD swizzle (nwg % 8 == 0)
  const int nwg = 128 * NB;
  const int orig = blockIdx.x;
  const int swz = (orig & 7) * (nwg >> 3) + (orig >> 3);
  const int bm = swz / NB, bn = swz % NB;
  const size_t m0 = (size_t)bm * 256;
  const int n0 = bn * 256;
  const bf16* Ab = A + m0 * C_;
  const bf16* Bb = Bt + (size_t)n0 * C_;

  f32x4 acc[8][4] = {};
  bf16x8 aA[4][2], bB[4][2];

#define STG(gbase, kt, buf, mat, h)                                           \
  { _Pragma("unroll") for (int i_ = 0; i_ < 2; i_++) {                        \
      int r_ = (h)*128 + i_*64 + wv*8 + lh;                                   \
      gload16(gbase + (size_t)r_ * C_ + (kt)*64 + lc8,                        \
              &sm[buf][mat][(h)*128 + i_*64 + wv*8][0]); } }

#define DSA(buf, mh)                                                          \
  { _Pragma("unroll") for (int mf_ = 0; mf_ < 4; mf_++) {                     \
      int r_ = wm*128 + (mh)*64 + mf_*16 + lr;                                \
      _Pragma("unroll") for (int s_ = 0; s_ < 2; s_++) {                      \
        int p_ = (s_*4 + lq) ^ l7;                                            \
        aA[mf_][s_] = *(const bf16x8*)&sm[buf][0][r_][p_*8]; } } }

#define DSB(buf, nh)                                                          \
  { _Pragma("unroll") for (int g_ = 0; g_ < 2; g_++) {                        \
      int r_ = wn*64 + ((nh)*2+g_)*16 + lr;                                   \
      _Pragma("unroll") for (int s_ = 0; s_ < 2; s_++) {                      \
        int p_ = (s_*4 + lq) ^ l7;                                            \
        bB[(nh)*2+g_][s_] = *(const bf16x8*)&sm[buf][1][r_][p_*8]; } } }

#define MFQ(mh, nh)                                                           \
  { _Pragma("unroll") for (int mf_ = 0; mf_ < 4; mf_++)                       \
    _Pragma("unroll") for (int g_ = 0; g_ < 2; g_++)                          \
    _Pragma("unroll") for (int s_ = 0; s_ < 2; s_++)                          \
      acc[(mh)*4+mf_][(nh)*2+g_] = __builtin_amdgcn_mfma_f32_16x16x32_bf16(   \
          aA[mf_][s_], bB[(nh)*2+g_][s_], acc[(mh)*4+mf_][(nh)*2+g_],0,0,0); }

#define SBAR()  asm volatile("s_barrier" ::: "memory")
#define LGKM0() { asm volatile("s_waitcnt lgkmcnt(0)" ::: "memory");          \
                  __builtin_amdgcn_sched_barrier(0); }
#define VMW(n)  { asm volatile("s_waitcnt vmcnt(" #n ")" ::: "memory");       \
                  __builtin_amdgcn_sched_barrier(0); }
#define PHI()   __builtin_amdgcn_s_setprio(1)
#define PLO()   { __builtin_amdgcn_s_setprio(0); __builtin_amdgcn_sched_barrier(0); }

  // ---- prologue: stage t0 fully + t1.B halves; allow t1.B outstanding ----
  STG(Ab, 0, 0, 0, 0); STG(Ab, 0, 0, 0, 1);
  STG(Bb, 0, 0, 1, 0); STG(Bb, 0, 0, 1, 1);
  STG(Bb, 1, 1, 1, 0); STG(Bb, 1, 1, 1, 1);
  VMW(4);
  SBAR();

  for (int i = 0; i < 4; i++) {
    const bool more = (i < 3);
    const int o = 2*i + 1, e2 = 2*i + 2, o2 = 2*i + 3;
    // P1
    DSA(0, 0); DSB(0, 0);
    STG(Ab, o, 1, 0, 0);
    SBAR(); LGKM0(); PHI(); MFQ(0, 0); PLO(); SBAR();
    // P2
    DSB(0, 1);
    STG(Ab, o, 1, 0, 1);
    SBAR(); LGKM0(); PHI(); MFQ(0, 1); PLO(); SBAR();
    // P3
    DSA(0, 1);
    if (more) STG(Bb, e2, 0, 1, 0);
    SBAR(); LGKM0(); PHI(); MFQ(1, 0); PLO(); SBAR();
    // P4
    if (more) STG(Bb, e2, 0, 1, 1);
    SBAR(); PHI(); MFQ(1, 1); PLO();
    if (more) { VMW(4); } else { VMW(0); }
    SBAR();
    // P5
    DSA(1, 0); DSB(1, 0);
    if (more) STG(Ab, e2, 0, 0, 0);
    SBAR(); LGKM0(); PHI(); MFQ(0, 0); PLO(); SBAR();
    // P6
    DSB(1, 1);
    if (more) STG(Ab, e2, 0, 0, 1);
    SBAR(); LGKM0(); PHI(); MFQ(0, 1); PLO(); SBAR();
    // P7
    DSA(1, 1);
    if (more) STG(Bb, o2, 1, 1, 0);
    SBAR(); LGKM0(); PHI(); MFQ(1, 0); PLO(); SBAR();
    // P8
    if (more) STG(Bb, o2, 1, 1, 1);
    SBAR(); PHI(); MFQ(1, 1); PLO();
    if (more) { VMW(4); }
    SBAR();
  }

  // ---- epilogue: C/D layout col = lane&15, row = (lane>>4)*4 + reg ----
#pragma unroll
  for (int F = 0; F < 8; F++) {
#pragma unroll
    for (int G = 0; G < 4; G++) {
      int j = n0 + wn*64 + G*16 + lr;
      float bj = bias[j];
      size_t mrow = m0 + wm*128 + F*16 + lq*4;
      if constexpr (QKV) {
        int mat = j >> 9, jj = j & 511;
        bf16* op = outb + (size_t)mat * ((size_t)M_ * C_);
#pragma unroll
        for (int r = 0; r < 4; r++)
          op[(mrow + r) * C_ + jj] = (bf16)(acc[F][G][r] + bj);
      } else {
#pragma unroll
        for (int r = 0; r < 4; r++)
          outf[(mrow + r) * C_ + j] = acc[F][G][r] + bj;
      }
    }
  }
#undef STG
#undef DSA
#undef DSB
#undef MFQ
#undef SBAR
#undef LGKM0
#undef VMW
#undef PHI
#undef PLO
}

// ---- kv partials: kvp[part][g][d][e] = sum_{n in part} k[n,d]*v[n,e] ----
__global__ __launch_bounds__(256)
void kv_kernel(const bf16* __restrict__ kmat, const bf16* __restrict__ vmat,
               float* __restrict__ kvp) {
  const int g = blockIdx.x & 255, part = blockIdx.x >> 8;
  const int tb = g >> 3, h = g & 7;
  const int w = threadIdx.x >> 6, l = threadIdx.x & 63;
  const bf16* kb = kmat + (size_t)tb * N_ * C_ + h * 64;
  const bf16* vb = vmat + (size_t)tb * N_ * C_ + h * 64;

  f32x4 acc[4] = {};
  for (int n0 = part * 256; n0 < part * 256 + 256; n0 += 32) {
    bf16x8 a, bv[4];
#pragma unroll
    for (int e = 0; e < 8; e++) {
      size_t row = (size_t)(n0 + (l >> 4) * 8 + e) * C_;
      a[e] = kb[row + 16 * w + (l & 15)];
#pragma unroll
      for (int nt = 0; nt < 4; nt++)
        bv[nt][e] = vb[row + nt * 16 + (l & 15)];
    }
#pragma unroll
    for (int nt = 0; nt < 4; nt++)
      acc[nt] = __builtin_amdgcn_mfma_f32_16x16x32_bf16(a, bv[nt], acc[nt], 0, 0, 0);
  }
#pragma unroll
  for (int nt = 0; nt < 4; nt++)
#pragma unroll
    for (int r = 0; r < 4; r++) {
      int d = 16 * w + (l >> 4) * 4 + r, e = nt * 16 + (l & 15);
      kvp[((size_t)(part * 256 + g)) * 4096 + d * 64 + e] = acc[nt][r];
    }
}

// ---- y[n][e] = sum_d q[n][d] * kv[d][e] ----
__global__ __launch_bounds__(256)
void y_kernel(const bf16* __restrict__ q, const float* __restrict__ kvp,
              bf16* __restrict__ y) {
  const int g = blockIdx.x >> 2, chunk = blockIdx.x & 3;
  const int tb = g >> 3, h = g & 7;
  const int w = threadIdx.x >> 6, l = threadIdx.x & 63;
  const bf16* qb = q + (size_t)tb * N_ * C_ + h * 64;
  bf16* yb = y + (size_t)tb * N_ * C_ + h * 64;

  bf16x8 bf[2][4];
#pragma unroll
  for (int ks = 0; ks < 2; ks++)
#pragma unroll
    for (int nt = 0; nt < 4; nt++)
#pragma unroll
      for (int e = 0; e < 8; e++) {
        int idx = (ks * 32 + (l >> 4) * 8 + e) * 64 + nt * 16 + (l & 15);
        float s = 0.f;
#pragma unroll
        for (int p = 0; p < 4; p++)
          s += kvp[((size_t)(p * 256 + g)) * 4096 + idx];
        bf[ks][nt][e] = (bf16)(s * (1.f / (float)N_));
      }

  for (int t = w; t < 16; t += 4) {
    int n0 = chunk * 256 + t * 16;
    f32x4 acc[4] = {};
#pragma unroll
    for (int ks = 0; ks < 2; ks++) {
      bf16x8 a = *(const bf16x8*)(qb + (size_t)(n0 + (l & 15)) * C_ + ks * 32 + (l >> 4) * 8);
#pragma unroll
      for (int nt = 0; nt < 4; nt++)
        acc[nt] = __builtin_amdgcn_mfma_f32_16x16x32_bf16(a, bf[ks][nt], acc[nt], 0, 0, 0);
    }
#pragma unroll
    for (int nt = 0; nt < 4; nt++)
#pragma unroll
      for (int r = 0; r < 4; r++) {
        int n = n0 + (l >> 4) * 4 + r, e = nt * 16 + (l & 15);
        yb[(size_t)n * C_ + e] = (bf16)acc[nt][r];
      }
  }
}

extern "C" void kernel_launch(void* const* d_in, const int* in_sizes, int n_in,
                              void* d_out, int out_size, void* d_ws, size_t ws_size,
                              hipStream_t stream) {
  const float* x = (const float*)d_in[0];
  char* ws = (char*)d_ws;
  bf16* xb   = (bf16*)(ws + 0);            // 33.5 MB, later reused as y
  bf16* q    = (bf16*)(ws + 33554432);
  bf16* kk   = (bf16*)(ws + 67108864);
  bf16* vv   = (bf16*)(ws + 100663296);
  float* kvp = (float*)(ws + 134217728);   // [4][256][64][64] f32 = 16 MB
  bf16* WB   = (bf16*)(ws + 150994944);    // [4][512][512] bf16 = 2 MB
  float* BS  = (float*)(ws + 153092096);   // [4][512] f32
  (void)in_sizes; (void)n_in; (void)out_size; (void)ws_size;

  for (int mat = 0; mat < 4; mat++) {
    const float* W    = (const float*)d_in[1 + 6 * mat + 0];
    const float* bb   = (const float*)d_in[1 + 6 * mat + 1];
    const float* gg   = (const float*)d_in[1 + 6 * mat + 2];
    const float* beta = (const float*)d_in[1 + 6 * mat + 3];
    const float* mu   = (const float*)d_in[1 + 6 * mat + 4];
    const float* var  = (const float*)d_in[1 + 6 * mat + 5];
    prep_w<<<512, 256, 0, stream>>>(W, bb, gg, beta, mu, var,
                                    WB + (size_t)mat * C_ * C_, BS + mat * C_);
  }
  cvt_x<<<2048, 256, 0, stream>>>(x, xb);
  gemm8<6, true><<<768, 512, 0, stream>>>(xb, WB, BS, q, nullptr);
  kv_kernel<<<1024, 256, 0, stream>>>(kk, vv, kvp);
  y_kernel<<<1024, 256, 0, stream>>>(q, kvp, xb /* = y */);
  gemm8<2, false><<<256, 512, 0, stream>>>(
      xb /* = y */, WB + 3 * (size_t)C_ * C_, BS + 3 * C_, nullptr, (float*)d_out);
}